// Round 9
// baseline (3501.071 us; speedup 1.0000x reference)
//
#include <hip/hip_runtime.h>

constexpr int kB = 256;
constexpr int kS = 512;
constexpr int kU = 256;

typedef _Float16 f16x2 __attribute__((ext_vector_type(2)));
typedef _Float16 f16x8 __attribute__((ext_vector_type(8)));
typedef float    f32x4 __attribute__((ext_vector_type(4)));
typedef unsigned u32x4 __attribute__((ext_vector_type(4)));

__device__ __forceinline__ float sigm(float x) {
    return 1.0f / (1.0f + __expf(-x));
}
__device__ __forceinline__ float tanh_fast(float x) {
    float ax = fabsf(x);
    float e = __expf(-2.0f * ax);
    float t = (1.0f - e) / (1.0f + e);
    return x < 0.0f ? -t : t;
}
__device__ __forceinline__ float dot2(unsigned w, unsigned h, float acc) {
    return __builtin_amdgcn_fdot2(__builtin_bit_cast(f16x2, w),
                                  __builtin_bit_cast(f16x2, h), acc, false);
}
__device__ __forceinline__ unsigned packh2(float lo, float hi) {
    f16x2 h; h.x = (_Float16)lo; h.y = (_Float16)hi;
    return __builtin_bit_cast(unsigned, h);
}
// byte offset of element (row m, col k) inside a frag-linear 16x256 fp16 A-tile
__device__ __forceinline__ int afrag_byte(int m, int k) {
    return (k >> 5) * 1024 + ((m & 15) + 16 * ((k >> 3) & 3)) * 16 + (k & 7) * 2;
}

// ws layout:
//   [0, 512K)    uint4 B-frag weights hU,fW,iW,cW (idx = mat*8192 + (nt*8+kt)*64 + lane)
//   [512K, 896K) packed-pair oW,tW,yW for phase 2
constexpr int kMatU32 = 32768;

__global__ __launch_bounds__(256) void convert_frag(
    const float* __restrict__ hU, const float* __restrict__ fW,
    const float* __restrict__ iW, const float* __restrict__ cW,
    uint4* __restrict__ wfrag)
{
    const int idx = blockIdx.x * 256 + threadIdx.x;   // 4*8192
    const int mat = idx >> 13;
    const int r   = idx & 8191;
    const int lane = r & 63;
    const int kt   = (r >> 6) & 7;
    const int nt   = r >> 9;
    const float* W = mat == 0 ? hU : mat == 1 ? fW : mat == 2 ? iW : cW;
    const int n  = nt * 16 + (lane & 15);
    const int k0 = kt * 32 + 8 * (lane >> 4);
    uint4 u;
    u.x = packh2(W[(k0 + 0) * kU + n], W[(k0 + 1) * kU + n]);
    u.y = packh2(W[(k0 + 2) * kU + n], W[(k0 + 3) * kU + n]);
    u.z = packh2(W[(k0 + 4) * kU + n], W[(k0 + 5) * kU + n]);
    u.w = packh2(W[(k0 + 6) * kU + n], W[(k0 + 7) * kU + n]);
    wfrag[idx] = u;
}

__global__ __launch_bounds__(256) void convert_pk(
    const float* __restrict__ oW, const float* __restrict__ tW,
    const float* __restrict__ yW, unsigned* __restrict__ wpk)
{
    const int idx = blockIdx.x * 256 + threadIdx.x;   // 3*32768
    const int mat = idx >> 15;
    const int r   = idx & (kMatU32 - 1);
    const int kp  = r >> 8;
    const int j   = r & 255;
    const float* W = mat == 0 ? oW : mat == 1 ? tW : yW;
    wpk[idx] = packh2(W[(2 * kp) * kU + j], W[(2 * kp + 1) * kU + j]);
}

// ---------------------------------------------------------------------------
// Phase 1: sequential recurrence, fully weight-resident per CU.
// 16 blocks x 256 threads (4 waves, 1 wave/SIMD -> 512 unified regs/wave).
// Wave w owns col tiles 4w..4w+3. Resident: hU in LDS (128 KB);
// fW,iW pinned to NAMED AGPR vars (256); cW pinned to NAMED VGPR vars (128).
// h/h1 in frag-linear LDS tiles; single fused gate pass (F,I,C per kt).
// Output: packed u32 (h fp16 low | h1 fp16 high) into d_out.
// ---------------------------------------------------------------------------

#define MFMA16(A, W, Acc) __builtin_amdgcn_mfma_f32_16x16x32_f16( \
    (A), __builtin_bit_cast(f16x8, (W)), (Acc), 0, 0, 0)

#define LOADW8(pre, moff, j)                                        \
  u32x4 pre##_0 = wfragv[(moff) + ((4*w+(j))*8+0)*64 + lane];       \
  u32x4 pre##_1 = wfragv[(moff) + ((4*w+(j))*8+1)*64 + lane];       \
  u32x4 pre##_2 = wfragv[(moff) + ((4*w+(j))*8+2)*64 + lane];       \
  u32x4 pre##_3 = wfragv[(moff) + ((4*w+(j))*8+3)*64 + lane];       \
  u32x4 pre##_4 = wfragv[(moff) + ((4*w+(j))*8+4)*64 + lane];       \
  u32x4 pre##_5 = wfragv[(moff) + ((4*w+(j))*8+5)*64 + lane];       \
  u32x4 pre##_6 = wfragv[(moff) + ((4*w+(j))*8+6)*64 + lane];       \
  u32x4 pre##_7 = wfragv[(moff) + ((4*w+(j))*8+7)*64 + lane];

#define PINA8(pre) asm volatile("" : "+a"(pre##_0), "+a"(pre##_1),  \
  "+a"(pre##_2), "+a"(pre##_3), "+a"(pre##_4), "+a"(pre##_5),       \
  "+a"(pre##_6), "+a"(pre##_7));
#define PINV8(pre) asm volatile("" : "+v"(pre##_0), "+v"(pre##_1),  \
  "+v"(pre##_2), "+v"(pre##_3), "+v"(pre##_4), "+v"(pre##_5),       \
  "+v"(pre##_6), "+v"(pre##_7));

#define GATE_KT(kt) {                                               \
  const f16x8 A = *(const f16x8*)(hAb + (kt) * 1024 + lane * 16);   \
  F[0] = MFMA16(A, wf0_##kt, F[0]);                                 \
  I[0] = MFMA16(A, wi0_##kt, I[0]);                                 \
  C[0] = MFMA16(A, wc0_##kt, C[0]);                                 \
  F[1] = MFMA16(A, wf1_##kt, F[1]);                                 \
  I[1] = MFMA16(A, wi1_##kt, I[1]);                                 \
  C[1] = MFMA16(A, wc1_##kt, C[1]);                                 \
  F[2] = MFMA16(A, wf2_##kt, F[2]);                                 \
  I[2] = MFMA16(A, wi2_##kt, I[2]);                                 \
  C[2] = MFMA16(A, wc2_##kt, C[2]);                                 \
  F[3] = MFMA16(A, wf3_##kt, F[3]);                                 \
  I[3] = MFMA16(A, wi3_##kt, I[3]);                                 \
  C[3] = MFMA16(A, wc3_##kt, C[3]); }

__global__ __launch_bounds__(256, 1) void rnn_phase1(
    const int* __restrict__ z,
    const float* __restrict__ hW, const float* __restrict__ hb,
    const float* __restrict__ fb, const float* __restrict__ ib,
    const float* __restrict__ cb,
    const float* __restrict__ h0,
    const uint4* __restrict__ wfrag,
    unsigned* __restrict__ outu)
{
    extern __shared__ __align__(16) char smem[];
    uint4* hUl  = (uint4*)smem;                // 131072 B
    char*  h1Ab = smem + 131072;               // 8192 B
    char*  hAb  = smem + 139264;               // 8192 B

    const int tid  = threadIdx.x;
    const int w    = tid >> 6;
    const int lane = tid & 63;
    const int m16  = lane & 15;
    const int g    = lane >> 4;
    const int b0   = blockIdx.x * 16;
    const int c0   = w * 64 + m16;             // col of tile j=0

    const u32x4* wfragv = (const u32x4*)wfrag;

    // one-time: hU into LDS
    for (int i = tid; i < 8192; i += 256) hUl[i] = wfrag[i];

    // named weight fragments: fW,iW -> AGPR (256), cW -> VGPR (128)
    LOADW8(wf0,  8192, 0) LOADW8(wf1,  8192, 1)
    LOADW8(wf2,  8192, 2) LOADW8(wf3,  8192, 3)
    LOADW8(wi0, 16384, 0) LOADW8(wi1, 16384, 1)
    LOADW8(wi2, 16384, 2) LOADW8(wi3, 16384, 3)
    LOADW8(wc0, 24576, 0) LOADW8(wc1, 24576, 1)
    LOADW8(wc2, 24576, 2) LOADW8(wc3, 24576, 3)
    PINA8(wf0) PINA8(wf1) PINA8(wf2) PINA8(wf3)
    PINA8(wi0) PINA8(wi1) PINA8(wi2) PINA8(wi3)
    PINV8(wc0) PINV8(wc1) PINV8(wc2) PINV8(wc3)

    float hbj[4], fbj[4], ibj[4], cbj[4];
    #pragma unroll
    for (int j = 0; j < 4; ++j) {
        hbj[j] = hb[c0 + 16 * j];
        fbj[j] = fb[c0 + 16 * j];
        ibj[j] = ib[c0 + 16 * j];
        cbj[j] = cb[c0 + 16 * j];
    }

    // h1 master fp32 (rows 4g+r, cols c0+16j)
    float h1m[4][4];
    #pragma unroll
    for (int j = 0; j < 4; ++j) {
        const float v = h0[c0 + 16 * j];
        #pragma unroll
        for (int r = 0; r < 4; ++r) h1m[j][r] = v;
    }
    // init h1A tile
    for (int i = tid; i < 16 * kU; i += 256) {
        const int m = i >> 8, k = i & 255;
        *(_Float16*)(h1Ab + afrag_byte(m, k)) = (_Float16)h0[k];
    }
    __syncthreads();

    unsigned obase[4];
    #pragma unroll
    for (int r = 0; r < 4; ++r)
        obase[r] = (unsigned)((b0 + 4 * g + r) * kS) * kU + c0;

    int zidx[4] = {0, 0, 0, 0};
    int znew[4] = {0, 0, 0, 0};

    for (int t = 0; t < kS; ++t) {
        // embedding gathers (consumed after hU mfma chain)
        float e[4][4];
        #pragma unroll
        for (int r = 0; r < 4; ++r) {
            const float* hwr = hW + (size_t)zidx[r] * kU;
            #pragma unroll
            for (int j = 0; j < 4; ++j) e[j][r] = hwr[c0 + 16 * j];
        }
        // prefetch z col t (forms zidx for step t+1)
        if (t < kS - 1) {
            #pragma unroll
            for (int r = 0; r < 4; ++r)
                znew[r] = z[(b0 + 4 * g + r) * kS + t];
        }

        // a = h1 @ hU  (A from LDS h1A, B from LDS hU)
        f32x4 a[4] = {{0.f,0.f,0.f,0.f},{0.f,0.f,0.f,0.f},
                      {0.f,0.f,0.f,0.f},{0.f,0.f,0.f,0.f}};
        #pragma unroll
        for (int kt = 0; kt < 8; ++kt) {
            const f16x8 A = *(const f16x8*)(h1Ab + kt * 1024 + lane * 16);
            #pragma unroll
            for (int j = 0; j < 4; ++j) {
                const f16x8 B = __builtin_bit_cast(f16x8,
                    hUl[((4 * w + j) * 8 + kt) * 64 + lane]);
                a[j] = __builtin_amdgcn_mfma_f32_16x16x32_f16(A, B, a[j], 0, 0, 0);
            }
        }

        // h = tanh(a + emb + hb) -> hA tile + keep in regs for output pack
        float hv[4][4];
        #pragma unroll
        for (int j = 0; j < 4; ++j)
            #pragma unroll
            for (int r = 0; r < 4; ++r) {
                hv[j][r] = tanh_fast(a[j][r] + e[j][r] + hbj[j]);
                *(_Float16*)(hAb + afrag_byte(4 * g + r, c0 + 16 * j)) =
                    (_Float16)hv[j][r];
            }
        __syncthreads();   // barrier 1: hA complete; h1A reads done

        // fused gate pass: F, I, C (register-resident B)
        f32x4 F[4] = {{0.f,0.f,0.f,0.f},{0.f,0.f,0.f,0.f},
                      {0.f,0.f,0.f,0.f},{0.f,0.f,0.f,0.f}};
        f32x4 I[4] = {{0.f,0.f,0.f,0.f},{0.f,0.f,0.f,0.f},
                      {0.f,0.f,0.f,0.f},{0.f,0.f,0.f,0.f}};
        f32x4 C[4] = {{0.f,0.f,0.f,0.f},{0.f,0.f,0.f,0.f},
                      {0.f,0.f,0.f,0.f},{0.f,0.f,0.f,0.f}};
        GATE_KT(0) GATE_KT(1) GATE_KT(2) GATE_KT(3)
        GATE_KT(4) GATE_KT(5) GATE_KT(6) GATE_KT(7)

        // update h1, pack (h,h1) output, refresh h1A tile
        const unsigned tOff = (unsigned)t * kU;
        #pragma unroll
        for (int j = 0; j < 4; ++j)
            #pragma unroll
            for (int r = 0; r < 4; ++r) {
                const float ff = sigm(F[j][r] + fbj[j]);
                const float ii = sigm(I[j][r] + ibj[j]);
                const float cc = tanh_fast(C[j][r] + cbj[j]);
                h1m[j][r] = h1m[j][r] * ff + cc * ii;
                const int m = 4 * g + r;
                outu[obase[r] + tOff + 16u * j] =
                    packh2(hv[j][r], h1m[j][r]);
                *(_Float16*)(h1Ab + afrag_byte(m, c0 + 16 * j)) =
                    (_Float16)h1m[j][r];
            }
        #pragma unroll
        for (int r = 0; r < 4; ++r) zidx[r] = znew[r] + 1;
        __syncthreads();   // barrier 2: h1A refreshed
    }
}

// ---------------------------------------------------------------------------
// Phase 2: output head. 4096 blocks x 256 threads, 32 rows/block.
// Reads packed (h,h1); o = sigm(h@oW+ob), g = o*h1, t = tanh(g@tW+tb),
// y = softmax(t@yW+yb). In-place on d_out.
// ---------------------------------------------------------------------------
__global__ __launch_bounds__(256) void rnn_phase2(
    const float* __restrict__ ob_, const float* __restrict__ tb,
    const float* __restrict__ yb,
    const unsigned* __restrict__ wpk,
    float* __restrict__ out)
{
    __shared__ unsigned pkl[32][kU];        // packed (h,h1) staging (32 KB)
    __shared__ unsigned xpk[32][kU / 2];    // packed pairs: h -> g -> t (16 KB)
    __shared__ float    lg[32][kU];         // logits (32 KB)

    const unsigned* __restrict__ oWpk = wpk;
    const unsigned* __restrict__ tWpk = wpk + kMatU32;
    const unsigned* __restrict__ yWpk = wpk + 2 * kMatU32;

    const int c = threadIdx.x;
    const size_t rowbase = (size_t)blockIdx.x * 32;
    unsigned* outu = (unsigned*)out;

    {
        const uint4* src = (const uint4*)(outu + rowbase * kU);
        uint4* dst = (uint4*)&pkl[0][0];
        #pragma unroll
        for (int i = 0; i < 8; ++i) dst[i * 256 + c] = src[i * 256 + c];
    }
    __syncthreads();

    // h packed pairs from low halves
    #pragma unroll
    for (int i = 0; i < 16; ++i) {
        const int flat = i * 256 + c;
        const int r = flat >> 7, kp = flat & 127;
        xpk[r][kp] = (pkl[r][2 * kp] & 0xFFFFu) | (pkl[r][2 * kp + 1] << 16);
    }
    __syncthreads();

    float acc[32];

    // ---- o = sigm(h @ oW + ob) ----
    {
        const float obc = ob_[c];
        #pragma unroll
        for (int r = 0; r < 32; ++r) acc[r] = obc;
    }
    #pragma unroll 2
    for (int kp4 = 0; kp4 < 32; ++kp4) {
        const unsigned w0 = oWpk[(4 * kp4 + 0) * kU + c];
        const unsigned w1 = oWpk[(4 * kp4 + 1) * kU + c];
        const unsigned w2 = oWpk[(4 * kp4 + 2) * kU + c];
        const unsigned w3 = oWpk[(4 * kp4 + 3) * kU + c];
        #pragma unroll
        for (int r = 0; r < 32; ++r) {
            const uint4 x = *(const uint4*)&xpk[r][4 * kp4];
            acc[r] = dot2(w0, x.x, acc[r]);
            acc[r] = dot2(w1, x.y, acc[r]);
            acc[r] = dot2(w2, x.z, acc[r]);
            acc[r] = dot2(w3, x.w, acc[r]);
        }
    }
    __syncthreads();   // all h-pair reads done

    // g = o * h1 ; repack pairs
    #pragma unroll
    for (int r = 0; r < 32; ++r) {
        const f16x2 pr = __builtin_bit_cast(f16x2, pkl[r][c]);
        const float gv = sigm(acc[r]) * (float)pr.y;
        const float gh = __shfl_down(gv, 1, 64);
        if ((c & 1) == 0) xpk[r][c >> 1] = packh2(gv, gh);
    }
    __syncthreads();

    // ---- t = tanh(g @ tW + tb) ----
    {
        const float tbc = tb[c];
        #pragma unroll
        for (int r = 0; r < 32; ++r) acc[r] = tbc;
    }
    #pragma unroll 2
    for (int kp4 = 0; kp4 < 32; ++kp4) {
        const unsigned w0 = tWpk[(4 * kp4 + 0) * kU + c];
        const unsigned w1 = tWpk[(4 * kp4 + 1) * kU + c];
        const unsigned w2 = tWpk[(4 * kp4 + 2) * kU + c];
        const unsigned w3 = tWpk[(4 * kp4 + 3) * kU + c];
        #pragma unroll
        for (int r = 0; r < 32; ++r) {
            const uint4 x = *(const uint4*)&xpk[r][4 * kp4];
            acc[r] = dot2(w0, x.x, acc[r]);
            acc[r] = dot2(w1, x.y, acc[r]);
            acc[r] = dot2(w2, x.z, acc[r]);
            acc[r] = dot2(w3, x.w, acc[r]);
        }
    }
    __syncthreads();

    #pragma unroll
    for (int r = 0; r < 32; ++r) {
        const float tv = tanh_fast(acc[r]);
        const float th = __shfl_down(tv, 1, 64);
        if ((c & 1) == 0) xpk[r][c >> 1] = packh2(tv, th);
    }
    __syncthreads();

    // ---- logits = t @ yW + yb ----
    {
        const float ybc = yb[c];
        #pragma unroll
        for (int r = 0; r < 32; ++r) acc[r] = ybc;
    }
    #pragma unroll 2
    for (int kp4 = 0; kp4 < 32; ++kp4) {
        const unsigned w0 = yWpk[(4 * kp4 + 0) * kU + c];
        const unsigned w1 = yWpk[(4 * kp4 + 1) * kU + c];
        const unsigned w2 = yWpk[(4 * kp4 + 2) * kU + c];
        const unsigned w3 = yWpk[(4 * kp4 + 3) * kU + c];
        #pragma unroll
        for (int r = 0; r < 32; ++r) {
            const uint4 x = *(const uint4*)&xpk[r][4 * kp4];
            acc[r] = dot2(w0, x.x, acc[r]);
            acc[r] = dot2(w1, x.y, acc[r]);
            acc[r] = dot2(w2, x.z, acc[r]);
            acc[r] = dot2(w3, x.w, acc[r]);
        }
    }

    #pragma unroll
    for (int r = 0; r < 32; ++r) lg[r][c] = acc[r];
    __syncthreads();

    // softmax: 4 waves x 8 rows each
    const int wv = c >> 6, lane = c & 63;
    for (int q = 0; q < 8; ++q) {
        const int r = wv * 8 + q;
        const float4 v = *(const float4*)&lg[r][lane * 4];
        float m = fmaxf(fmaxf(v.x, v.y), fmaxf(v.z, v.w));
        #pragma unroll
        for (int off = 32; off > 0; off >>= 1) m = fmaxf(m, __shfl_xor(m, off, 64));
        const float e0 = __expf(v.x - m), e1 = __expf(v.y - m);
        const float e2 = __expf(v.z - m), e3 = __expf(v.w - m);
        float s = e0 + e1 + e2 + e3;
        #pragma unroll
        for (int off = 32; off > 0; off >>= 1) s += __shfl_xor(s, off, 64);
        const float inv = 1.0f / s;
        float4 o4; o4.x = e0 * inv; o4.y = e1 * inv; o4.z = e2 * inv; o4.w = e3 * inv;
        *(float4*)&out[(rowbase + r) * kU + lane * 4] = o4;
    }
}

extern "C" void kernel_launch(void* const* d_in, const int* in_sizes, int n_in,
                              void* d_out, int out_size, void* d_ws, size_t ws_size,
                              hipStream_t stream) {
    const int*   z  = (const int*)d_in[0];
    const float* hW = (const float*)d_in[1];
    const float* hU = (const float*)d_in[2];
    const float* hb = (const float*)d_in[3];
    const float* fW = (const float*)d_in[4];
    const float* fb = (const float*)d_in[5];
    const float* iW = (const float*)d_in[6];
    const float* ib = (const float*)d_in[7];
    const float* cW = (const float*)d_in[8];
    const float* cb = (const float*)d_in[9];
    const float* oW = (const float*)d_in[10];
    const float* ob = (const float*)d_in[11];
    const float* tW = (const float*)d_in[12];
    const float* tb = (const float*)d_in[13];
    const float* yW = (const float*)d_in[14];
    const float* yb = (const float*)d_in[15];
    const float* h0 = (const float*)d_in[16];
    float* out = (float*)d_out;

    uint4*    wfrag = (uint4*)d_ws;                   // 4*8192 uint4 = 512 KB
    unsigned* wpk   = (unsigned*)d_ws + 4 * kMatU32;  // oW,tW,yW packed pairs

    hipFuncSetAttribute((const void*)rnn_phase1,
                        hipFuncAttributeMaxDynamicSharedMemorySize, 147456);

    convert_frag<<<dim3(4 * 8192 / 256), dim3(256), 0, stream>>>(
        hU, fW, iW, cW, wfrag);
    convert_pk<<<dim3(3 * kMatU32 / 256), dim3(256), 0, stream>>>(
        oW, tW, yW, wpk);
    rnn_phase1<<<dim3(kB / 16), dim3(256), 147456, stream>>>(
        z, hW, hb, fb, ib, cb, h0, wfrag, (unsigned*)out);
    rnn_phase2<<<dim3((kB * kS) / 32), dim3(256), 0, stream>>>(
        ob, tb, yb, wpk, out);
}

// Round 10
// 3459.955 us; speedup vs baseline: 1.0119x; 1.0119x over previous
//
#include <hip/hip_runtime.h>

constexpr int kB = 256;
constexpr int kS = 512;
constexpr int kU = 256;

typedef _Float16 f16x2 __attribute__((ext_vector_type(2)));
typedef _Float16 f16x8 __attribute__((ext_vector_type(8)));
typedef float    f32x4 __attribute__((ext_vector_type(4)));
typedef unsigned u32x4 __attribute__((ext_vector_type(4)));

__device__ __forceinline__ float sigm(float x) {
    return 1.0f / (1.0f + __expf(-x));
}
__device__ __forceinline__ float tanh_fast(float x) {
    float ax = fabsf(x);
    float e = __expf(-2.0f * ax);
    float t = (1.0f - e) / (1.0f + e);
    return x < 0.0f ? -t : t;
}
__device__ __forceinline__ float dot2(unsigned w, unsigned h, float acc) {
    return __builtin_amdgcn_fdot2(__builtin_bit_cast(f16x2, w),
                                  __builtin_bit_cast(f16x2, h), acc, false);
}
__device__ __forceinline__ unsigned packh2(float lo, float hi) {
    f16x2 h; h.x = (_Float16)lo; h.y = (_Float16)hi;
    return __builtin_bit_cast(unsigned, h);
}
// byte offset of element (row m, col k) inside a frag-linear 16x256 fp16 A-tile
__device__ __forceinline__ int afrag_byte(int m, int k) {
    return (k >> 5) * 1024 + ((m & 15) + 16 * ((k >> 3) & 3)) * 16 + (k & 7) * 2;
}

// ws layout:
//   [0, 512K)    uint4 B-frag weights hU,fW,iW,cW (idx = mat*8192 + (nt*8+kt)*64 + lane)
//   [512K, 896K) packed-pair oW,tW,yW for phase 2
constexpr int kMatU32 = 32768;

__global__ __launch_bounds__(256) void convert_frag(
    const float* __restrict__ hU, const float* __restrict__ fW,
    const float* __restrict__ iW, const float* __restrict__ cW,
    uint4* __restrict__ wfrag)
{
    const int idx = blockIdx.x * 256 + threadIdx.x;   // 4*8192
    const int mat = idx >> 13;
    const int r   = idx & 8191;
    const int lane = r & 63;
    const int kt   = (r >> 6) & 7;
    const int nt   = r >> 9;
    const float* W = mat == 0 ? hU : mat == 1 ? fW : mat == 2 ? iW : cW;
    const int n  = nt * 16 + (lane & 15);
    const int k0 = kt * 32 + 8 * (lane >> 4);
    uint4 u;
    u.x = packh2(W[(k0 + 0) * kU + n], W[(k0 + 1) * kU + n]);
    u.y = packh2(W[(k0 + 2) * kU + n], W[(k0 + 3) * kU + n]);
    u.z = packh2(W[(k0 + 4) * kU + n], W[(k0 + 5) * kU + n]);
    u.w = packh2(W[(k0 + 6) * kU + n], W[(k0 + 7) * kU + n]);
    wfrag[idx] = u;
}

__global__ __launch_bounds__(256) void convert_pk(
    const float* __restrict__ oW, const float* __restrict__ tW,
    const float* __restrict__ yW, unsigned* __restrict__ wpk)
{
    const int idx = blockIdx.x * 256 + threadIdx.x;   // 3*32768
    const int mat = idx >> 15;
    const int r   = idx & (kMatU32 - 1);
    const int kp  = r >> 8;
    const int j   = r & 255;
    const float* W = mat == 0 ? oW : mat == 1 ? tW : yW;
    wpk[idx] = packh2(W[(2 * kp) * kU + j], W[(2 * kp + 1) * kU + j]);
}

// ---------------------------------------------------------------------------
// Phase 1: sequential recurrence, weight-resident, 2 waves/SIMD.
// 16 blocks x 512 threads (8 waves). 16 batch rows per block (M=16).
// Wave w owns col tiles nt0=2w, nt1=2w+1 (cols 32w..32w+31).
// Resident: hU in LDS (128 KB); fW,iW pinned AGPR (128), cW pinned VGPR (64)
// per wave = 192 weight regs; __launch_bounds__(512,2) caps at 256 -> 2 w/SIMD.
// h/h1 in frag-linear LDS tiles; 2 barriers/step. No oW here.
// Output: packed u32 (h fp16 low | h1 fp16 high) into d_out.
// ---------------------------------------------------------------------------

#define MFMA16(A, W, Acc) __builtin_amdgcn_mfma_f32_16x16x32_f16( \
    (A), __builtin_bit_cast(f16x8, (W)), (Acc), 0, 0, 0)

#define LOADW8(pre, moff, nt)                                       \
  u32x4 pre##_0 = wfragv[(moff) + ((nt)*8+0)*64 + lane];            \
  u32x4 pre##_1 = wfragv[(moff) + ((nt)*8+1)*64 + lane];            \
  u32x4 pre##_2 = wfragv[(moff) + ((nt)*8+2)*64 + lane];            \
  u32x4 pre##_3 = wfragv[(moff) + ((nt)*8+3)*64 + lane];            \
  u32x4 pre##_4 = wfragv[(moff) + ((nt)*8+4)*64 + lane];            \
  u32x4 pre##_5 = wfragv[(moff) + ((nt)*8+5)*64 + lane];            \
  u32x4 pre##_6 = wfragv[(moff) + ((nt)*8+6)*64 + lane];            \
  u32x4 pre##_7 = wfragv[(moff) + ((nt)*8+7)*64 + lane];

#define PINA8(pre) asm volatile("" : "+a"(pre##_0), "+a"(pre##_1),  \
  "+a"(pre##_2), "+a"(pre##_3), "+a"(pre##_4), "+a"(pre##_5),       \
  "+a"(pre##_6), "+a"(pre##_7));
#define PINV8(pre) asm volatile("" : "+v"(pre##_0), "+v"(pre##_1),  \
  "+v"(pre##_2), "+v"(pre##_3), "+v"(pre##_4), "+v"(pre##_5),       \
  "+v"(pre##_6), "+v"(pre##_7));

#define GATE_KT(kt) {                                               \
  const f16x8 A = *(const f16x8*)(hAb + (kt) * 1024 + lane * 16);   \
  F0 = MFMA16(A, wfA_##kt, F0);                                     \
  I0 = MFMA16(A, wiA_##kt, I0);                                     \
  C0 = MFMA16(A, wcA_##kt, C0);                                     \
  F1 = MFMA16(A, wfB_##kt, F1);                                     \
  I1 = MFMA16(A, wiB_##kt, I1);                                     \
  C1 = MFMA16(A, wcB_##kt, C1); }

__global__ __launch_bounds__(512, 2) void rnn_phase1(
    const int* __restrict__ z,
    const float* __restrict__ hW, const float* __restrict__ hb,
    const float* __restrict__ fb, const float* __restrict__ ib,
    const float* __restrict__ cb,
    const float* __restrict__ h0,
    const uint4* __restrict__ wfrag,
    unsigned* __restrict__ outu)
{
    extern __shared__ __align__(16) char smem[];
    uint4* hUl  = (uint4*)smem;                // 131072 B
    char*  h1Ab = smem + 131072;               // 8192 B
    char*  hAb  = smem + 139264;               // 8192 B

    const int tid  = threadIdx.x;
    const int w    = tid >> 6;                 // 0..7
    const int lane = tid & 63;
    const int m16  = lane & 15;
    const int g    = lane >> 4;
    const int b0   = blockIdx.x * 16;
    const int nt0  = 2 * w, nt1 = nt0 + 1;
    const int c0   = 32 * w + m16;             // col of tile 0
    const int c1   = c0 + 16;                  // col of tile 1

    const u32x4* wfragv = (const u32x4*)wfrag;

    // one-time: hU into LDS
    for (int i = tid; i < 8192; i += 512) hUl[i] = wfrag[i];

    // named weight fragments: fW,iW -> AGPR (128), cW -> VGPR (64)
    LOADW8(wfA,  8192, nt0) LOADW8(wfB,  8192, nt1)
    LOADW8(wiA, 16384, nt0) LOADW8(wiB, 16384, nt1)
    LOADW8(wcA, 24576, nt0) LOADW8(wcB, 24576, nt1)
    PINA8(wfA) PINA8(wfB) PINA8(wiA) PINA8(wiB)
    PINV8(wcA) PINV8(wcB)

    const float hb0 = hb[c0], hb1 = hb[c1];
    const float fb0 = fb[c0], fb1 = fb[c1];
    const float ib0 = ib[c0], ib1 = ib[c1];
    const float cb0 = cb[c0], cb1 = cb[c1];

    // h1 master fp32 (rows 4g+r, cols c0/c1)
    float h1m0[4], h1m1[4];
    {
        const float v0 = h0[c0], v1 = h0[c1];
        #pragma unroll
        for (int r = 0; r < 4; ++r) { h1m0[r] = v0; h1m1[r] = v1; }
    }
    // init h1A tile (cooperative)
    for (int i = tid; i < 16 * kU; i += 512) {
        const int m = i >> 8, k = i & 255;
        *(_Float16*)(h1Ab + afrag_byte(m, k)) = (_Float16)h0[k];
    }
    __syncthreads();

    // output base for row 4g (row r adds r<<17, step t adds t*256)
    const unsigned obase0 = (unsigned)((b0 + 4 * g) * kS) * kU + c0;

    for (int t = 0; t < kS; ++t) {
        // embedding gathers (z -> hW chain, issued early)
        float e0[4], e1[4];
        #pragma unroll
        for (int r = 0; r < 4; ++r) {
            int zt = 0;
            if (t > 0) zt = z[(b0 + 4 * g + r) * kS + t - 1] + 1;
            const float* hwr = hW + (size_t)zt * kU;
            e0[r] = hwr[c0];
            e1[r] = hwr[c1];
        }

        // a = h1 @ hU  (A from LDS h1A, B from LDS hU)
        f32x4 a0 = {0.f, 0.f, 0.f, 0.f}, a1 = {0.f, 0.f, 0.f, 0.f};
        #pragma unroll
        for (int kt = 0; kt < 8; ++kt) {
            const f16x8 A = *(const f16x8*)(h1Ab + kt * 1024 + lane * 16);
            const f16x8 B0 = __builtin_bit_cast(f16x8, hUl[(nt0 * 8 + kt) * 64 + lane]);
            const f16x8 B1 = __builtin_bit_cast(f16x8, hUl[(nt1 * 8 + kt) * 64 + lane]);
            a0 = __builtin_amdgcn_mfma_f32_16x16x32_f16(A, B0, a0, 0, 0, 0);
            a1 = __builtin_amdgcn_mfma_f32_16x16x32_f16(A, B1, a1, 0, 0, 0);
        }

        // h = tanh(a + emb + hb) -> hA tile + keep in regs for output pack
        float hv0[4], hv1[4];
        #pragma unroll
        for (int r = 0; r < 4; ++r) {
            hv0[r] = tanh_fast(a0[r] + e0[r] + hb0);
            hv1[r] = tanh_fast(a1[r] + e1[r] + hb1);
            *(_Float16*)(hAb + afrag_byte(4 * g + r, c0)) = (_Float16)hv0[r];
            *(_Float16*)(hAb + afrag_byte(4 * g + r, c1)) = (_Float16)hv1[r];
        }
        __syncthreads();   // barrier 1: hA complete; h1A reads done

        // fused gate pass: F, I, C for both tiles (register-resident B)
        f32x4 F0 = {0.f,0.f,0.f,0.f}, F1 = {0.f,0.f,0.f,0.f};
        f32x4 I0 = {0.f,0.f,0.f,0.f}, I1 = {0.f,0.f,0.f,0.f};
        f32x4 C0 = {0.f,0.f,0.f,0.f}, C1 = {0.f,0.f,0.f,0.f};
        GATE_KT(0) GATE_KT(1) GATE_KT(2) GATE_KT(3)
        GATE_KT(4) GATE_KT(5) GATE_KT(6) GATE_KT(7)

        // update h1, pack (h,h1) output, refresh h1A tile
        const unsigned tOff = (unsigned)t * kU;
        #pragma unroll
        for (int r = 0; r < 4; ++r) {
            const int m = 4 * g + r;
            {
                const float ff = sigm(F0[r] + fb0);
                const float ii = sigm(I0[r] + ib0);
                const float cc = tanh_fast(C0[r] + cb0);
                h1m0[r] = h1m0[r] * ff + cc * ii;
                outu[obase0 + ((unsigned)r << 17) + tOff] =
                    packh2(hv0[r], h1m0[r]);
                *(_Float16*)(h1Ab + afrag_byte(m, c0)) = (_Float16)h1m0[r];
            }
            {
                const float ff = sigm(F1[r] + fb1);
                const float ii = sigm(I1[r] + ib1);
                const float cc = tanh_fast(C1[r] + cb1);
                h1m1[r] = h1m1[r] * ff + cc * ii;
                outu[obase0 + ((unsigned)r << 17) + tOff + 16] =
                    packh2(hv1[r], h1m1[r]);
                *(_Float16*)(h1Ab + afrag_byte(m, c1)) = (_Float16)h1m1[r];
            }
        }
        __syncthreads();   // barrier 2: h1A refreshed
    }
}

// ---------------------------------------------------------------------------
// Phase 2: output head. 4096 blocks x 256 threads, 32 rows/block.
// Reads packed (h,h1); o = sigm(h@oW+ob), g = o*h1, t = tanh(g@tW+tb),
// y = softmax(t@yW+yb). In-place on d_out.
// ---------------------------------------------------------------------------
__global__ __launch_bounds__(256) void rnn_phase2(
    const float* __restrict__ ob_, const float* __restrict__ tb,
    const float* __restrict__ yb,
    const unsigned* __restrict__ wpk,
    float* __restrict__ out)
{
    __shared__ unsigned pkl[32][kU];        // packed (h,h1) staging (32 KB)
    __shared__ unsigned xpk[32][kU / 2];    // packed pairs: h -> g -> t (16 KB)
    __shared__ float    lg[32][kU];         // logits (32 KB)

    const unsigned* __restrict__ oWpk = wpk;
    const unsigned* __restrict__ tWpk = wpk + kMatU32;
    const unsigned* __restrict__ yWpk = wpk + 2 * kMatU32;

    const int c = threadIdx.x;
    const size_t rowbase = (size_t)blockIdx.x * 32;
    unsigned* outu = (unsigned*)out;

    {
        const uint4* src = (const uint4*)(outu + rowbase * kU);
        uint4* dst = (uint4*)&pkl[0][0];
        #pragma unroll
        for (int i = 0; i < 8; ++i) dst[i * 256 + c] = src[i * 256 + c];
    }
    __syncthreads();

    // h packed pairs from low halves
    #pragma unroll
    for (int i = 0; i < 16; ++i) {
        const int flat = i * 256 + c;
        const int r = flat >> 7, kp = flat & 127;
        xpk[r][kp] = (pkl[r][2 * kp] & 0xFFFFu) | (pkl[r][2 * kp + 1] << 16);
    }
    __syncthreads();

    float acc[32];

    // ---- o = sigm(h @ oW + ob) ----
    {
        const float obc = ob_[c];
        #pragma unroll
        for (int r = 0; r < 32; ++r) acc[r] = obc;
    }
    #pragma unroll 2
    for (int kp4 = 0; kp4 < 32; ++kp4) {
        const unsigned w0 = oWpk[(4 * kp4 + 0) * kU + c];
        const unsigned w1 = oWpk[(4 * kp4 + 1) * kU + c];
        const unsigned w2 = oWpk[(4 * kp4 + 2) * kU + c];
        const unsigned w3 = oWpk[(4 * kp4 + 3) * kU + c];
        #pragma unroll
        for (int r = 0; r < 32; ++r) {
            const uint4 x = *(const uint4*)&xpk[r][4 * kp4];
            acc[r] = dot2(w0, x.x, acc[r]);
            acc[r] = dot2(w1, x.y, acc[r]);
            acc[r] = dot2(w2, x.z, acc[r]);
            acc[r] = dot2(w3, x.w, acc[r]);
        }
    }
    __syncthreads();   // all h-pair reads done

    // g = o * h1 ; repack pairs
    #pragma unroll
    for (int r = 0; r < 32; ++r) {
        const f16x2 pr = __builtin_bit_cast(f16x2, pkl[r][c]);
        const float gv = sigm(acc[r]) * (float)pr.y;
        const float gh = __shfl_down(gv, 1, 64);
        if ((c & 1) == 0) xpk[r][c >> 1] = packh2(gv, gh);
    }
    __syncthreads();

    // ---- t = tanh(g @ tW + tb) ----
    {
        const float tbc = tb[c];
        #pragma unroll
        for (int r = 0; r < 32; ++r) acc[r] = tbc;
    }
    #pragma unroll 2
    for (int kp4 = 0; kp4 < 32; ++kp4) {
        const unsigned w0 = tWpk[(4 * kp4 + 0) * kU + c];
        const unsigned w1 = tWpk[(4 * kp4 + 1) * kU + c];
        const unsigned w2 = tWpk[(4 * kp4 + 2) * kU + c];
        const unsigned w3 = tWpk[(4 * kp4 + 3) * kU + c];
        #pragma unroll
        for (int r = 0; r < 32; ++r) {
            const uint4 x = *(const uint4*)&xpk[r][4 * kp4];
            acc[r] = dot2(w0, x.x, acc[r]);
            acc[r] = dot2(w1, x.y, acc[r]);
            acc[r] = dot2(w2, x.z, acc[r]);
            acc[r] = dot2(w3, x.w, acc[r]);
        }
    }
    __syncthreads();

    #pragma unroll
    for (int r = 0; r < 32; ++r) {
        const float tv = tanh_fast(acc[r]);
        const float th = __shfl_down(tv, 1, 64);
        if ((c & 1) == 0) xpk[r][c >> 1] = packh2(tv, th);
    }
    __syncthreads();

    // ---- logits = t @ yW + yb ----
    {
        const float ybc = yb[c];
        #pragma unroll
        for (int r = 0; r < 32; ++r) acc[r] = ybc;
    }
    #pragma unroll 2
    for (int kp4 = 0; kp4 < 32; ++kp4) {
        const unsigned w0 = yWpk[(4 * kp4 + 0) * kU + c];
        const unsigned w1 = yWpk[(4 * kp4 + 1) * kU + c];
        const unsigned w2 = yWpk[(4 * kp4 + 2) * kU + c];
        const unsigned w3 = yWpk[(4 * kp4 + 3) * kU + c];
        #pragma unroll
        for (int r = 0; r < 32; ++r) {
            const uint4 x = *(const uint4*)&xpk[r][4 * kp4];
            acc[r] = dot2(w0, x.x, acc[r]);
            acc[r] = dot2(w1, x.y, acc[r]);
            acc[r] = dot2(w2, x.z, acc[r]);
            acc[r] = dot2(w3, x.w, acc[r]);
        }
    }

    #pragma unroll
    for (int r = 0; r < 32; ++r) lg[r][c] = acc[r];
    __syncthreads();

    // softmax: 4 waves x 8 rows each
    const int wv = c >> 6, lane = c & 63;
    for (int q = 0; q < 8; ++q) {
        const int r = wv * 8 + q;
        const float4 v = *(const float4*)&lg[r][lane * 4];
        float m = fmaxf(fmaxf(v.x, v.y), fmaxf(v.z, v.w));
        #pragma unroll
        for (int off = 32; off > 0; off >>= 1) m = fmaxf(m, __shfl_xor(m, off, 64));
        const float e0 = __expf(v.x - m), e1 = __expf(v.y - m);
        const float e2 = __expf(v.z - m), e3 = __expf(v.w - m);
        float s = e0 + e1 + e2 + e3;
        #pragma unroll
        for (int off = 32; off > 0; off >>= 1) s += __shfl_xor(s, off, 64);
        const float inv = 1.0f / s;
        float4 o4; o4.x = e0 * inv; o4.y = e1 * inv; o4.z = e2 * inv; o4.w = e3 * inv;
        *(float4*)&out[(rowbase + r) * kU + lane * 4] = o4;
    }
}

extern "C" void kernel_launch(void* const* d_in, const int* in_sizes, int n_in,
                              void* d_out, int out_size, void* d_ws, size_t ws_size,
                              hipStream_t stream) {
    const int*   z  = (const int*)d_in[0];
    const float* hW = (const float*)d_in[1];
    const float* hU = (const float*)d_in[2];
    const float* hb = (const float*)d_in[3];
    const float* fW = (const float*)d_in[4];
    const float* fb = (const float*)d_in[5];
    const float* iW = (const float*)d_in[6];
    const float* ib = (const float*)d_in[7];
    const float* cW = (const float*)d_in[8];
    const float* cb = (const float*)d_in[9];
    const float* oW = (const float*)d_in[10];
    const float* ob = (const float*)d_in[11];
    const float* tW = (const float*)d_in[12];
    const float* tb = (const float*)d_in[13];
    const float* yW = (const float*)d_in[14];
    const float* yb = (const float*)d_in[15];
    const float* h0 = (const float*)d_in[16];
    float* out = (float*)d_out;

    uint4*    wfrag = (uint4*)d_ws;                   // 4*8192 uint4 = 512 KB
    unsigned* wpk   = (unsigned*)d_ws + 4 * kMatU32;  // oW,tW,yW packed pairs

    hipFuncSetAttribute((const void*)rnn_phase1,
                        hipFuncAttributeMaxDynamicSharedMemorySize, 147456);

    convert_frag<<<dim3(4 * 8192 / 256), dim3(256), 0, stream>>>(
        hU, fW, iW, cW, wfrag);
    convert_pk<<<dim3(3 * kMatU32 / 256), dim3(256), 0, stream>>>(
        oW, tW, yW, wpk);
    rnn_phase1<<<dim3(kB / 16), dim3(512), 147456, stream>>>(
        z, hW, hb, fb, ib, cb, h0, wfrag, (unsigned*)out);
    rnn_phase2<<<dim3((kB * kS) / 32), dim3(256), 0, stream>>>(
        ob, tb, yb, wpk, out);
}

// Round 11
// 1990.028 us; speedup vs baseline: 1.7593x; 1.7386x over previous
//
#include <hip/hip_runtime.h>

constexpr int kB = 256;
constexpr int kS = 512;
constexpr int kU = 256;

typedef _Float16 f16x2 __attribute__((ext_vector_type(2)));
typedef _Float16 f16x8 __attribute__((ext_vector_type(8)));
typedef float    f32x4 __attribute__((ext_vector_type(4)));
typedef unsigned u32x4 __attribute__((ext_vector_type(4)));

// fast activations: v_rcp-based (no Newton-refined division). ~1 ulp rcp error,
// negligible vs fp16 storage quantum.
__device__ __forceinline__ float sigm(float x) {
    return __builtin_amdgcn_rcpf(1.0f + __expf(-x));
}
__device__ __forceinline__ float tanh_fast(float x) {
    const float ex = __expf(2.0f * x);
    return 1.0f - 2.0f * __builtin_amdgcn_rcpf(ex + 1.0f);
}
__device__ __forceinline__ unsigned packh2(float lo, float hi) {
    f16x2 h; h.x = (_Float16)lo; h.y = (_Float16)hi;
    return __builtin_bit_cast(unsigned, h);
}
// byte offset of element (row m, col k) inside a frag-linear 16x256 fp16 A-tile
__device__ __forceinline__ int afrag_byte(int m, int k) {
    return (k >> 5) * 1024 + ((m & 15) + 16 * ((k >> 3) & 3)) * 16 + (k & 7) * 2;
}

// ---------------------------------------------------------------------------
// ws: uint4 B-frag weights for all 7 matrices, PERMUTED column order:
//   idx = mat*8192 + (nt*8 + kt)*64 + lane
//   lane l in tile nt holds TRUE column n = 32*(nt>>1) + 2*(l&15) + (nt&1)
//   (so a lane owning tiles (2q, 2q+1) at slot m16 owns ADJACENT cols
//    32q+2*m16, 32q+2*m16+1 -> all LDS/global writes pair into b32/uint2)
//   mats: 0=hU 1=fW 2=iW 3=cW 4=oW 5=tW 6=yW
// ---------------------------------------------------------------------------
__global__ __launch_bounds__(256) void convert_frag(
    const float* __restrict__ hU, const float* __restrict__ fW,
    const float* __restrict__ iW, const float* __restrict__ cW,
    const float* __restrict__ oW, const float* __restrict__ tW,
    const float* __restrict__ yW, uint4* __restrict__ wfrag)
{
    const int idx = blockIdx.x * 256 + threadIdx.x;   // 7*8192
    const int mat = idx >> 13;
    const int r   = idx & 8191;
    const int lane = r & 63;
    const int kt   = (r >> 6) & 7;
    const int nt   = r >> 9;
    const float* W = mat == 0 ? hU : mat == 1 ? fW : mat == 2 ? iW :
                     mat == 3 ? cW : mat == 4 ? oW : mat == 5 ? tW : yW;
    const int n  = 32 * (nt >> 1) + 2 * (lane & 15) + (nt & 1);
    const int k0 = kt * 32 + 8 * (lane >> 4);
    uint4 u;
    u.x = packh2(W[(k0 + 0) * kU + n], W[(k0 + 1) * kU + n]);
    u.y = packh2(W[(k0 + 2) * kU + n], W[(k0 + 3) * kU + n]);
    u.z = packh2(W[(k0 + 4) * kU + n], W[(k0 + 5) * kU + n]);
    u.w = packh2(W[(k0 + 6) * kU + n], W[(k0 + 7) * kU + n]);
    wfrag[idx] = u;
}

// ---------------------------------------------------------------------------
// Phase 1: sequential recurrence, weight-resident, 2 waves/SIMD.
// 16 blocks x 512 threads (8 waves). Wave w owns tiles nt0=2w, nt1=2w+1 =
// true cols 32w+2*m16 (+1). hU in LDS (128 KB); fW,iW pinned AGPR (128),
// cW pinned VGPR (64). h/h1 in frag-linear LDS A-tiles; paired b32 writes.
// Output: packed u32 (h fp16 lo | h1 fp16 hi), uint2 per lane per row.
// ---------------------------------------------------------------------------

#define MFMA16(A, W, Acc) __builtin_amdgcn_mfma_f32_16x16x32_f16( \
    (A), __builtin_bit_cast(f16x8, (W)), (Acc), 0, 0, 0)

#define LOADW8(pre, moff, nt)                                       \
  u32x4 pre##_0 = wfragv[(moff) + ((nt)*8+0)*64 + lane];            \
  u32x4 pre##_1 = wfragv[(moff) + ((nt)*8+1)*64 + lane];            \
  u32x4 pre##_2 = wfragv[(moff) + ((nt)*8+2)*64 + lane];            \
  u32x4 pre##_3 = wfragv[(moff) + ((nt)*8+3)*64 + lane];            \
  u32x4 pre##_4 = wfragv[(moff) + ((nt)*8+4)*64 + lane];            \
  u32x4 pre##_5 = wfragv[(moff) + ((nt)*8+5)*64 + lane];            \
  u32x4 pre##_6 = wfragv[(moff) + ((nt)*8+6)*64 + lane];            \
  u32x4 pre##_7 = wfragv[(moff) + ((nt)*8+7)*64 + lane];

#define PINA8(pre) asm volatile("" : "+a"(pre##_0), "+a"(pre##_1),  \
  "+a"(pre##_2), "+a"(pre##_3), "+a"(pre##_4), "+a"(pre##_5),       \
  "+a"(pre##_6), "+a"(pre##_7));
#define PINV8(pre) asm volatile("" : "+v"(pre##_0), "+v"(pre##_1),  \
  "+v"(pre##_2), "+v"(pre##_3), "+v"(pre##_4), "+v"(pre##_5),       \
  "+v"(pre##_6), "+v"(pre##_7));

#define GATE_KT(kt) {                                               \
  const f16x8 A = *(const f16x8*)(hAb + (kt) * 1024 + lane * 16);   \
  F0 = MFMA16(A, wfA_##kt, F0);                                     \
  I0 = MFMA16(A, wiA_##kt, I0);                                     \
  C0 = MFMA16(A, wcA_##kt, C0);                                     \
  F1 = MFMA16(A, wfB_##kt, F1);                                     \
  I1 = MFMA16(A, wiB_##kt, I1);                                     \
  C1 = MFMA16(A, wcB_##kt, C1); }

__global__ __launch_bounds__(512, 2) void rnn_phase1(
    const int* __restrict__ z,
    const float* __restrict__ hW, const float* __restrict__ hb,
    const float* __restrict__ fb, const float* __restrict__ ib,
    const float* __restrict__ cb,
    const float* __restrict__ h0,
    const uint4* __restrict__ wfrag,
    unsigned* __restrict__ outu)
{
    extern __shared__ __align__(16) char smem[];
    uint4* hUl  = (uint4*)smem;                // 131072 B
    char*  h1Ab = smem + 131072;               // 8192 B
    char*  hAb  = smem + 139264;               // 8192 B

    const int tid  = threadIdx.x;
    const int w    = tid >> 6;                 // 0..7
    const int lane = tid & 63;
    const int m16  = lane & 15;
    const int g    = lane >> 4;
    const int b0   = blockIdx.x * 16;
    const int nt0  = 2 * w, nt1 = nt0 + 1;
    const int c0   = 32 * w + 2 * m16;         // true col (even); c1 = c0+1

    const u32x4* wfragv = (const u32x4*)wfrag;

    for (int i = tid; i < 8192; i += 512) hUl[i] = wfrag[i];

    LOADW8(wfA,  8192, nt0) LOADW8(wfB,  8192, nt1)
    LOADW8(wiA, 16384, nt0) LOADW8(wiB, 16384, nt1)
    LOADW8(wcA, 24576, nt0) LOADW8(wcB, 24576, nt1)
    PINA8(wfA) PINA8(wfB) PINA8(wiA) PINA8(wiB)
    PINV8(wcA) PINV8(wcB)

    const float2 hb2 = *(const float2*)&hb[c0];
    const float2 fb2 = *(const float2*)&fb[c0];
    const float2 ib2 = *(const float2*)&ib[c0];
    const float2 cb2 = *(const float2*)&cb[c0];

    float h1m0[4], h1m1[4];
    {
        const float2 h02 = *(const float2*)&h0[c0];
        #pragma unroll
        for (int r = 0; r < 4; ++r) { h1m0[r] = h02.x; h1m1[r] = h02.y; }
    }
    // init h1A tile (paired b32 writes)
    for (int i = tid; i < 2048; i += 512) {
        const int m = i >> 7, kp = i & 127;
        *(unsigned*)(h1Ab + afrag_byte(m, 2 * kp)) =
            packh2(h0[2 * kp], h0[2 * kp + 1]);
    }
    __syncthreads();

    const unsigned obase0 = (unsigned)((b0 + 4 * g) * kS) * kU + c0;

    for (int t = 0; t < kS; ++t) {
        // embedding gathers (float2: adjacent true cols)
        float2 e2[4];
        #pragma unroll
        for (int r = 0; r < 4; ++r) {
            int zt = 0;
            if (t > 0) zt = z[(b0 + 4 * g + r) * kS + t - 1] + 1;
            e2[r] = *(const float2*)&hW[(size_t)zt * kU + c0];
        }

        // a = h1 @ hU
        f32x4 a0 = {0.f, 0.f, 0.f, 0.f}, a1 = {0.f, 0.f, 0.f, 0.f};
        #pragma unroll
        for (int kt = 0; kt < 8; ++kt) {
            const f16x8 A = *(const f16x8*)(h1Ab + kt * 1024 + lane * 16);
            const f16x8 B0 = __builtin_bit_cast(f16x8, hUl[(nt0 * 8 + kt) * 64 + lane]);
            const f16x8 B1 = __builtin_bit_cast(f16x8, hUl[(nt1 * 8 + kt) * 64 + lane]);
            a0 = __builtin_amdgcn_mfma_f32_16x16x32_f16(A, B0, a0, 0, 0, 0);
            a1 = __builtin_amdgcn_mfma_f32_16x16x32_f16(A, B1, a1, 0, 0, 0);
        }

        // h = tanh(a + emb + hb) -> hA (one b32 per row pair)
        float hv0[4], hv1[4];
        #pragma unroll
        for (int r = 0; r < 4; ++r) {
            hv0[r] = tanh_fast(a0[r] + e2[r].x + hb2.x);
            hv1[r] = tanh_fast(a1[r] + e2[r].y + hb2.y);
            *(unsigned*)(hAb + afrag_byte(4 * g + r, c0)) = packh2(hv0[r], hv1[r]);
        }
        __syncthreads();   // barrier 1: hA complete; h1A reads done

        // fused gate pass: F, I, C (register-resident B)
        f32x4 F0 = {0.f,0.f,0.f,0.f}, F1 = {0.f,0.f,0.f,0.f};
        f32x4 I0 = {0.f,0.f,0.f,0.f}, I1 = {0.f,0.f,0.f,0.f};
        f32x4 C0 = {0.f,0.f,0.f,0.f}, C1 = {0.f,0.f,0.f,0.f};
        GATE_KT(0) GATE_KT(1) GATE_KT(2) GATE_KT(3)
        GATE_KT(4) GATE_KT(5) GATE_KT(6) GATE_KT(7)

        // update h1, pack (h,h1) uint2 store, refresh h1A (b32)
        const unsigned tOff = (unsigned)t * kU;
        #pragma unroll
        for (int r = 0; r < 4; ++r) {
            const float ff0 = sigm(F0[r] + fb2.x);
            const float ii0 = sigm(I0[r] + ib2.x);
            const float cc0 = tanh_fast(C0[r] + cb2.x);
            const float ff1 = sigm(F1[r] + fb2.y);
            const float ii1 = sigm(I1[r] + ib2.y);
            const float cc1 = tanh_fast(C1[r] + cb2.y);
            h1m0[r] = h1m0[r] * ff0 + cc0 * ii0;
            h1m1[r] = h1m1[r] * ff1 + cc1 * ii1;
            uint2 ov;
            ov.x = packh2(hv0[r], h1m0[r]);
            ov.y = packh2(hv1[r], h1m1[r]);
            *(uint2*)&outu[obase0 + ((unsigned)r << 17) + tOff] = ov;
            *(unsigned*)(h1Ab + afrag_byte(4 * g + r, c0)) =
                packh2(h1m0[r], h1m1[r]);
        }
        __syncthreads();   // barrier 2: h1A refreshed
    }
}

// ---------------------------------------------------------------------------
// Phase 2: output head, MFMA version. 4096 blocks x 256 threads (4 waves),
// 32 rows/block. o = sigm(h@oW+ob), g = o*h1, tt = tanh(g@tW+tb),
// y = softmax(tt@yW+yb). A-tiles rebuilt in LDS per matvec (h -> g -> tt).
// Wave w owns nt 4w..4w+3; permuted cols make conv writes paired b32/float2.
// ---------------------------------------------------------------------------
#define P2_MATVEC(MOFF)                                                   \
  {                                                                       \
    f16x8 Af[2][8];                                                       \
    _Pragma("unroll") for (int kt = 0; kt < 8; ++kt) {                    \
      Af[0][kt] = *(const f16x8*)(aT + kt * 1024 + lane * 16);            \
      Af[1][kt] = *(const f16x8*)(aT + 8192 + kt * 1024 + lane * 16);     \
    }                                                                     \
    _Pragma("unroll") for (int ntl = 0; ntl < 4; ++ntl) {                 \
      const int nt = 4 * w + ntl;                                         \
      acc[0][ntl] = (f32x4){0.f, 0.f, 0.f, 0.f};                          \
      acc[1][ntl] = (f32x4){0.f, 0.f, 0.f, 0.f};                          \
      _Pragma("unroll") for (int kt = 0; kt < 8; ++kt) {                  \
        const f16x8 Bf = __builtin_bit_cast(f16x8,                        \
            wfrag[(MOFF) + (nt * 8 + kt) * 64 + lane]);                   \
        acc[0][ntl] = __builtin_amdgcn_mfma_f32_16x16x32_f16(             \
            Af[0][kt], Bf, acc[0][ntl], 0, 0, 0);                         \
        acc[1][ntl] = __builtin_amdgcn_mfma_f32_16x16x32_f16(             \
            Af[1][kt], Bf, acc[1][ntl], 0, 0, 0);                         \
      }                                                                   \
    }                                                                     \
  }

__global__ __launch_bounds__(256, 2) void rnn_phase2(
    const float* __restrict__ ob_, const float* __restrict__ tb,
    const float* __restrict__ yb,
    const uint4* __restrict__ wfrag,
    float* __restrict__ out)
{
    extern __shared__ __align__(16) char smem[];
    unsigned* pkl = (unsigned*)smem;           // 32*256 u32 = 32768 B
    char*     aT  = smem + 32768;              // 2 A-tiles = 16384 B
    float*    lg  = (float*)(smem + 49152);    // logits 32768 B

    const int tid  = threadIdx.x;
    const int w    = tid >> 6;
    const int lane = tid & 63;
    const int m16  = lane & 15;
    const int g    = lane >> 4;
    const size_t rowbase = (size_t)blockIdx.x * 32;
    unsigned* outu = (unsigned*)out;

    // stage packed (h,h1)
    {
        const uint4* src = (const uint4*)(outu + rowbase * kU);
        uint4* dst = (uint4*)pkl;
        #pragma unroll
        for (int i = 0; i < 8; ++i) dst[i * 256 + tid] = src[i * 256 + tid];
    }
    __syncthreads();

    // build h A-tiles (lo halves, paired b32)
    for (int i = tid; i < 4096; i += 256) {
        const int row = i >> 7, kp = i & 127;
        const unsigned p0 = pkl[row * 256 + 2 * kp];
        const unsigned p1 = pkl[row * 256 + 2 * kp + 1];
        *(unsigned*)(aT + (row >> 4) * 8192 + afrag_byte(row & 15, 2 * kp)) =
            (p0 & 0xFFFFu) | (p1 << 16);
    }
    __syncthreads();

    const int cA = 64 * w + 2 * m16;   // true col of acc[.][0]; [1] = cA+1
    const int cB = cA + 32;            // true col of acc[.][2]; [3] = cB+1

    f32x4 acc[2][4];

    // ---- o = sigm(h @ oW + ob); g = o * h1 -> gA tiles ----
    P2_MATVEC(4 * 8192)
    __syncthreads();   // all h A-reads done before overwrite
    {
        const float2 obA = *(const float2*)&ob_[cA];
        const float2 obB = *(const float2*)&ob_[cB];
        #pragma unroll
        for (int mt = 0; mt < 2; ++mt) {
            #pragma unroll
            for (int r = 0; r < 4; ++r) {
                const int row = mt * 16 + 4 * g + r;
                const f16x2 qA0 = __builtin_bit_cast(f16x2, pkl[row * 256 + cA]);
                const f16x2 qA1 = __builtin_bit_cast(f16x2, pkl[row * 256 + cA + 1]);
                const f16x2 qB0 = __builtin_bit_cast(f16x2, pkl[row * 256 + cB]);
                const f16x2 qB1 = __builtin_bit_cast(f16x2, pkl[row * 256 + cB + 1]);
                const float g0 = sigm(acc[mt][0][r] + obA.x) * (float)qA0.y;
                const float g1 = sigm(acc[mt][1][r] + obA.y) * (float)qA1.y;
                const float g2 = sigm(acc[mt][2][r] + obB.x) * (float)qB0.y;
                const float g3 = sigm(acc[mt][3][r] + obB.y) * (float)qB1.y;
                char* tile = aT + mt * 8192;
                *(unsigned*)(tile + afrag_byte(row & 15, cA)) = packh2(g0, g1);
                *(unsigned*)(tile + afrag_byte(row & 15, cB)) = packh2(g2, g3);
            }
        }
    }
    __syncthreads();

    // ---- tt = tanh(g @ tW + tb) -> ttA tiles ----
    P2_MATVEC(5 * 8192)
    __syncthreads();
    {
        const float2 tbA = *(const float2*)&tb[cA];
        const float2 tbB = *(const float2*)&tb[cB];
        #pragma unroll
        for (int mt = 0; mt < 2; ++mt) {
            #pragma unroll
            for (int r = 0; r < 4; ++r) {
                const int row = mt * 16 + 4 * g + r;
                const float t0 = tanh_fast(acc[mt][0][r] + tbA.x);
                const float t1 = tanh_fast(acc[mt][1][r] + tbA.y);
                const float t2 = tanh_fast(acc[mt][2][r] + tbB.x);
                const float t3 = tanh_fast(acc[mt][3][r] + tbB.y);
                char* tile = aT + mt * 8192;
                *(unsigned*)(tile + afrag_byte(row & 15, cA)) = packh2(t0, t1);
                *(unsigned*)(tile + afrag_byte(row & 15, cB)) = packh2(t2, t3);
            }
        }
    }
    __syncthreads();

    // ---- logits = tt @ yW + yb -> lg ----
    P2_MATVEC(6 * 8192)
    {
        const float2 ybA = *(const float2*)&yb[cA];
        const float2 ybB = *(const float2*)&yb[cB];
        #pragma unroll
        for (int mt = 0; mt < 2; ++mt) {
            #pragma unroll
            for (int r = 0; r < 4; ++r) {
                const int row = mt * 16 + 4 * g + r;
                float2 lA, lB;
                lA.x = acc[mt][0][r] + ybA.x;  lA.y = acc[mt][1][r] + ybA.y;
                lB.x = acc[mt][2][r] + ybB.x;  lB.y = acc[mt][3][r] + ybB.y;
                *(float2*)&lg[row * 256 + cA] = lA;
                *(float2*)&lg[row * 256 + cB] = lB;
            }
        }
    }
    __syncthreads();

    // softmax: 4 waves x 8 rows each
    for (int q = 0; q < 8; ++q) {
        const int r = w * 8 + q;
        const float4 v = *(const float4*)&lg[r * 256 + lane * 4];
        float m = fmaxf(fmaxf(v.x, v.y), fmaxf(v.z, v.w));
        #pragma unroll
        for (int off = 32; off > 0; off >>= 1) m = fmaxf(m, __shfl_xor(m, off, 64));
        const float e0 = __expf(v.x - m), e1 = __expf(v.y - m);
        const float e2 = __expf(v.z - m), e3 = __expf(v.w - m);
        float s = e0 + e1 + e2 + e3;
        #pragma unroll
        for (int off = 32; off > 0; off >>= 1) s += __shfl_xor(s, off, 64);
        const float inv = 1.0f / s;
        float4 o4; o4.x = e0 * inv; o4.y = e1 * inv; o4.z = e2 * inv; o4.w = e3 * inv;
        *(float4*)&out[(rowbase + r) * kU + lane * 4] = o4;
    }
}

extern "C" void kernel_launch(void* const* d_in, const int* in_sizes, int n_in,
                              void* d_out, int out_size, void* d_ws, size_t ws_size,
                              hipStream_t stream) {
    const int*   z  = (const int*)d_in[0];
    const float* hW = (const float*)d_in[1];
    const float* hU = (const float*)d_in[2];
    const float* hb = (const float*)d_in[3];
    const float* fW = (const float*)d_in[4];
    const float* fb = (const float*)d_in[5];
    const float* iW = (const float*)d_in[6];
    const float* ib = (const float*)d_in[7];
    const float* cW = (const float*)d_in[8];
    const float* cb = (const float*)d_in[9];
    const float* oW = (const float*)d_in[10];
    const float* ob = (const float*)d_in[11];
    const float* tW = (const float*)d_in[12];
    const float* tb = (const float*)d_in[13];
    const float* yW = (const float*)d_in[14];
    const float* yb = (const float*)d_in[15];
    const float* h0 = (const float*)d_in[16];
    float* out = (float*)d_out;

    uint4* wfrag = (uint4*)d_ws;    // 7*8192 uint4 = 896 KB

    hipFuncSetAttribute((const void*)rnn_phase1,
                        hipFuncAttributeMaxDynamicSharedMemorySize, 147456);
    hipFuncSetAttribute((const void*)rnn_phase2,
                        hipFuncAttributeMaxDynamicSharedMemorySize, 81920);

    convert_frag<<<dim3(7 * 8192 / 256), dim3(256), 0, stream>>>(
        hU, fW, iW, cW, oW, tW, yW, wfrag);
    rnn_phase1<<<dim3(kB / 16), dim3(512), 147456, stream>>>(
        z, hW, hb, fb, ib, cb, h0, wfrag, (unsigned*)out);
    rnn_phase2<<<dim3((kB * kS) / 32), dim3(256), 81920, stream>>>(
        ob, tb, yb, wfrag, out);
}